// Round 11
// baseline (88.298 us; speedup 1.0000x reference)
//
#include <hip/hip_runtime.h>

#define BS 128
#define T 256
#define D 1024
#define NCAT 2688
#define NFEAT 1024

typedef short bf16x8 __attribute__((ext_vector_type(8)));
typedef float f32x4 __attribute__((ext_vector_type(4)));
typedef unsigned short u16;
typedef u16 u16x4 __attribute__((ext_vector_type(4)));

__device__ __forceinline__ u16 f2bf(float f) {
    unsigned int u = __float_as_uint(f);
    u += 0x7fffu + ((u >> 16) & 1u);   // round-to-nearest-even
    return (u16)(u >> 16);
}

// ---------------------------------------------------------------------------
// ka — one launch, four independent roles (no cross-block deps):
//  [0,128):     POOL: batch b, read all 256 rows (L3-warming, fixed loop),
//               gv/lv computed directly -> cat[gv], lv_bf. No partials.
//  [128,1152):  COPY: pure 32-row chunk copy vf -> out0 (no mask logic).
//  [1152,4864): CONVERT: W1,W2,W4 f32 -> bf16.
//  [4864,4992): TAIL: sen -> cat(bf16)+out1(f32), loc head -> cat.
// cat layout: [sen 0..1023 | gv 1024..2047 | vs 2048..2559 | loc 2560..2687]
// ---------------------------------------------------------------------------
__global__ __launch_bounds__(256, 4)
void ka(const float* __restrict__ vf, float* __restrict__ out0,
        const int* __restrict__ vmask, const float* __restrict__ loc,
        const float* __restrict__ sen_fea,
        const float* __restrict__ W1, const float* __restrict__ W2,
        const float* __restrict__ W3, const float* __restrict__ W4,
        const float* __restrict__ b3,
        u16* __restrict__ W1b, u16* __restrict__ W2b, u16* __restrict__ W4b,
        u16* __restrict__ cat, u16* __restrict__ lv, float* __restrict__ out1) {
    int blk = blockIdx.x, tid = threadIdx.x;

    if (blk < 128) {
        // ---- POOL role: direct gv/lv for batch b ----
        int b = blk;
        __shared__ int red[256];
        __shared__ int sse[3];
        red[tid] = vmask[b * T + tid];
        __syncthreads();
        for (int off = 128; off > 0; off >>= 1) {
            if (tid < off) red[tid] += red[tid + off];
            __syncthreads();
        }
        if (tid == 0) {
            int vl = red[0];
            float sc = (float)(vl - 1);
            sse[0] = vl;
            sse[1] = (int)floorf(loc[2 * b] * sc);
            sse[2] = (int)floorf(loc[2 * b + 1] * sc);
        }
        __syncthreads();
        int vl = sse[0], s = sse[1], e = sse[2];

        int d0 = tid * 4;
        f32x4 g  = {0.f, 0.f, 0.f, 0.f};
        f32x4 sg = {0.f, 0.f, 0.f, 0.f};
        const float* src = vf + (size_t)b * T * D + d0;
#pragma unroll 8
        for (int t = 0; t < 256; ++t) {      // fixed bound, deep MLP
            f32x4 v = *(const f32x4*)src;
            if (t < vl) g += v;
            if (t >= s && t <= e) sg += v;
            src += D;
        }
        float inv_vl = 1.0f / (float)vl;
        int cnt = e + 1 - s; if (cnt < 1) cnt = 1;
        float inv_cnt = 1.0f / (float)cnt;
        bool valid = (s <= e);
        u16x4 og, ol;
#pragma unroll
        for (int j = 0; j < 4; ++j) {
            og[j] = f2bf(g[j] * inv_vl);
            ol[j] = f2bf(valid ? sg[j] * inv_cnt : 0.f);
        }
        *(u16x4*)(cat + b * NCAT + 1024 + d0) = og;
        *(u16x4*)(lv + b * D + d0) = ol;
        return;
    }

    if (blk < 1152) {
        // ---- COPY role: pure streaming copy, no mask logic ----
        int ci = blk - 128;
        int b = ci >> 3, tc = ci & 7;
        int d0 = tid * 4;
        const float* src = vf   + ((size_t)(b * T + tc * 32)) * D + d0;
        float*       dst = out0 + ((size_t)(b * T + tc * 32)) * D + d0;
        for (int i = 0; i < 32; ++i) {       // fixed bound -> unrolled
            f32x4 v = *(const f32x4*)src;
            __builtin_nontemporal_store(v, (f32x4*)dst);
            src += D; dst += D;
        }
        return;
    }

    if (blk < 4864) {
        // ---- CONVERT role ----
        int i = (blk - 1152) * 256 + tid;    // float4 index, 950272 total
        const float* src; u16* dst;
        if (i < 131072)      { src = W1 + 4 * i;            dst = W1b + 4 * i; }
        else if (i < 262144) { src = W2 + 4 * (i - 131072); dst = W2b + 4 * (i - 131072); }
        else                 { src = W4 + 4 * (i - 262144); dst = W4b + 4 * (i - 262144); }
        f32x4 v = *(const f32x4*)src;
        u16x4 o;
        o[0] = f2bf(v[0]); o[1] = f2bf(v[1]); o[2] = f2bf(v[2]); o[3] = f2bf(v[3]);
        *(u16x4*)dst = o;
        return;
    }

    // ---- TAIL role: sen/loc ----
    {
        int b = blk - 4864;
        int d0 = tid * 4;
        f32x4 sf = *(const f32x4*)(sen_fea + b * D + d0);
        *(f32x4*)(out1 + b * D + d0) = sf;
        u16x4 sb;
        sb[0] = f2bf(sf[0]); sb[1] = f2bf(sf[1]); sb[2] = f2bf(sf[2]); sb[3] = f2bf(sf[3]);
        *(u16x4*)(cat + b * NCAT + d0) = sb;
        if (tid < 128) {
            float v = loc[2 * b] * W3[2 * tid] + loc[2 * b + 1] * W3[2 * tid + 1] + b3[tid];
            cat[b * NCAT + 2560 + tid] = f2bf(fmaxf(v, 0.f));
        }
    }
}

// ---------------------------------------------------------------------------
// kBC: ONE launch, two independent roles (disjoint cat regions -> no race):
//  [0,128):   k3 — vs = relu((lv@W1^T+b1)*(sen@W2^T+b2)) -> cat[vs].
//  [128,640): k4a — partial feature GEMM over K = [0,2048) u [2560,2688)
//             (no vs dependency): wave w owns cols [512w,512w+512); wave 0
//             additionally owns the 128 loc cols. split LDS-reduced -> part.
// ---------------------------------------------------------------------------
__global__ void kBC(const u16* __restrict__ lv, const u16* __restrict__ cat_ro,
                    const u16* __restrict__ W1b, const float* __restrict__ b1,
                    const u16* __restrict__ W2b, const float* __restrict__ b2,
                    const u16* __restrict__ W4b, u16* __restrict__ cat,
                    float* __restrict__ part) {
    int blk = blockIdx.x, tid = threadIdx.x;

    if (blk < 128) {
        // ---------------- k3 ----------------
        __shared__ float qs[2][4][64];
        int mt = blk >> 4, ntg = blk & 15;
        int sub = tid >> 7, chain = (tid >> 6) & 1, lane = tid & 63;
        int m0 = mt * 16, n0 = ntg * 32 + sub * 16;
        int row = lane & 15, kg = lane >> 4;

        const u16* pa = chain ? (cat_ro + (m0 + row) * NCAT + kg * 8)   // sen
                              : (lv     + (m0 + row) * D    + kg * 8);
        const u16* pb = (chain ? W2b : W1b) + (n0 + row) * D + kg * 8;

        f32x4 acc = {0.f, 0.f, 0.f, 0.f};
        for (int k = 0; k < 1024; k += 32)
            acc = __builtin_amdgcn_mfma_f32_16x16x32_bf16(*(const bf16x8*)(pa + k),
                                                          *(const bf16x8*)(pb + k),
                                                          acc, 0, 0, 0);
        int col = lane & 15, rbase = (lane >> 4) * 4;
        float bb = (chain ? b2 : b1)[n0 + col];
        if (chain) {
#pragma unroll
            for (int r = 0; r < 4; ++r) qs[sub][r][lane] = acc[r] + bb;
        }
        __syncthreads();
        if (!chain) {
#pragma unroll
            for (int r = 0; r < 4; ++r) {
                float p = acc[r] + bb;
                cat[(m0 + rbase + r) * NCAT + 2048 + n0 + col] =
                    f2bf(fmaxf(p * qs[sub][r][lane], 0.f));
            }
        }
        return;
    }

    // ---------------- k4a: K = [0,2048) + [2560,2688), branch-free ----------------
    __shared__ float qsf[3][4][64];
    int bi = blk - 128;                      // [0,512)
    int mt = bi >> 6, nt = bi & 63;
    int wid = tid >> 6, lane = tid & 63;
    int m0 = mt * 16, n0 = nt * 16;
    int row = lane & 15, kg = lane >> 4;

    const u16* pa = cat_ro + (m0 + row) * NCAT + kg * 8;
    const u16* pb = W4b    + (n0 + row) * NCAT + kg * 8;

    f32x4 acc = {0.f, 0.f, 0.f, 0.f};
    int kb = wid * 512;
    for (int k = 0; k < 512; k += 32)        // fixed bound
        acc = __builtin_amdgcn_mfma_f32_16x16x32_bf16(*(const bf16x8*)(pa + kb + k),
                                                      *(const bf16x8*)(pb + kb + k),
                                                      acc, 0, 0, 0);
    if (wid == 0) {                          // loc columns [2560,2688)
        for (int k = 2560; k < 2688; k += 32)
            acc = __builtin_amdgcn_mfma_f32_16x16x32_bf16(*(const bf16x8*)(pa + k),
                                                          *(const bf16x8*)(pb + k),
                                                          acc, 0, 0, 0);
    }
    if (wid) {
#pragma unroll
        for (int r = 0; r < 4; ++r) qsf[wid - 1][r][lane] = acc[r];
    }
    __syncthreads();
    if (wid == 0) {
#pragma unroll
        for (int r = 0; r < 4; ++r)
            part[bi * 256 + r * 64 + lane] =
                acc[r] + qsf[0][r][lane] + qsf[1][r][lane] + qsf[2][r][lane];
    }
}

// ---------------------------------------------------------------------------
// k4b: finish feature GEMM — vs columns (K=512) + stored partial + bias, relu.
// 512 blocks x 128 thr: 2 waves x K=256, LDS swap, wave0 writes.
// ---------------------------------------------------------------------------
__global__ void k4b(const u16* __restrict__ cat, const u16* __restrict__ W4b,
                    const float* __restrict__ b4, const float* __restrict__ part,
                    float* __restrict__ out2) {
    int blk = blockIdx.x, tid = threadIdx.x;
    __shared__ float qs[4][64];

    int mt = blk >> 6, nt = blk & 63;
    int wid = tid >> 6, lane = tid & 63;
    int m0 = mt * 16, n0 = nt * 16;
    int row = lane & 15, kg = lane >> 4;

    const u16* pa = cat + (m0 + row) * NCAT + 2048 + wid * 256 + kg * 8;
    const u16* pb = W4b + (n0 + row) * NCAT + 2048 + wid * 256 + kg * 8;

    f32x4 acc = {0.f, 0.f, 0.f, 0.f};
    for (int k = 0; k < 256; k += 32)
        acc = __builtin_amdgcn_mfma_f32_16x16x32_bf16(*(const bf16x8*)(pa + k),
                                                      *(const bf16x8*)(pb + k),
                                                      acc, 0, 0, 0);
    int col = lane & 15, rbase = (lane >> 4) * 4;
    if (wid == 1) {
#pragma unroll
        for (int r = 0; r < 4; ++r) qs[r][lane] = acc[r];
    }
    __syncthreads();
    if (wid == 0) {
        float bb = b4[n0 + col];
#pragma unroll
        for (int r = 0; r < 4; ++r) {
            float v = acc[r] + qs[r][lane] + part[blk * 256 + r * 64 + lane] + bb;
            out2[(m0 + rbase + r) * NFEAT + n0 + col] = fmaxf(v, 0.f);
        }
    }
}

// ---------------------------------------------------------------------------
extern "C" void kernel_launch(void* const* d_in, const int* in_sizes, int n_in,
                              void* d_out, int out_size, void* d_ws, size_t ws_size,
                              hipStream_t stream) {
    (void)in_sizes; (void)n_in; (void)out_size; (void)ws_size;
    const float* vf      = (const float*)d_in[3];
    const float* sen_fea = (const float*)d_in[4];
    const float* loc     = (const float*)d_in[5];
    const int*   vmask   = (const int*)d_in[7];
    const float* W1 = (const float*)d_in[8];
    const float* b1 = (const float*)d_in[9];
    const float* W2 = (const float*)d_in[10];
    const float* b2 = (const float*)d_in[11];
    const float* W3 = (const float*)d_in[12];
    const float* b3 = (const float*)d_in[13];
    const float* W4 = (const float*)d_in[14];
    const float* b4 = (const float*)d_in[15];

    float* out0 = (float*)d_out;
    float* out1 = out0 + (size_t)BS * T * D;
    float* out2 = out1 + (size_t)BS * D;

    char* w = (char*)d_ws;
    u16*   cat  = (u16*)  (w);                         // 688128 B
    u16*   W1b  = (u16*)  (w + (1 << 20));             // 1 MB
    u16*   W2b  = (u16*)  (w + (2 << 20));             // 1 MB
    u16*   W4b  = (u16*)  (w + (3 << 20));             // 5.25 MB
    float* part = (float*)(w + (9 << 20));             // 512 KB
    u16*   lv   = (u16*)  (w + (10 << 20));            // 256 KB

    ka<<<4992, 256, 0, stream>>>(vf, out0, vmask, loc, sen_fea,
                                 W1, W2, W3, W4, b3,
                                 W1b, W2b, W4b, cat, lv, out1);
    kBC<<<640, 256, 0, stream>>>(lv, cat, W1b, b1, W2b, b2, W4b, cat, part);
    k4b<<<512, 128, 0, stream>>>(cat, W4b, b4, part, out2);
}